// Round 7
// baseline (58.813 us; speedup 1.0000x reference)
//
#include <hip/hip_runtime.h>
#include <hip/hip_bf16.h>

#define NS     256
#define FEAT   8192
#define BD     128
#define CD     16
#define NOUT   2048
#define OUTW   8320              // FEAT + BD
#define KSPLIT 16
#define KC     (FEAT / KSPLIT)   // 512
#define BK     32
#define NSTEP  (KC / BK)         // 16
#define BM     256
#define BN     128
#define BBP    40                // Bbf pitch in shorts (80 B -> uniform banks)

typedef float f32x4 __attribute__((ext_vector_type(4)));
typedef short bf16x8 __attribute__((ext_vector_type(8)));
typedef short bf16x4 __attribute__((ext_vector_type(4)));

typedef unsigned int u32;
typedef __attribute__((address_space(3))) u32 lds_u32;
typedef const __attribute__((address_space(1))) u32 gbl_u32;

// direct global->LDS, 16 B per lane; LDS dest = wave-uniform base + lane*16.
__device__ __forceinline__ void gl_lds16(const void* g, void* l) {
    __builtin_amdgcn_global_load_lds((gbl_u32*)g, (lds_u32*)l, 16, 0, 0);
}

__device__ __forceinline__ bf16x4 cvt4(float a, float b, float c, float d) {
    union { __hip_bfloat162 h[2]; bf16x4 s; } u;
    u.h[0] = __float22bfloat162_rn(float2{a, b});
    u.h[1] = __float22bfloat162_rn(float2{c, d});
    return u.s;
}

__device__ __forceinline__ f32x4 bf4_to_f32(bf16x4 s) {
    f32x4 r;
    r.x = __uint_as_float(((u32)(unsigned short)s.x) << 16);
    r.y = __uint_as_float(((u32)(unsigned short)s.y) << 16);
    r.z = __uint_as_float(((u32)(unsigned short)s.z) << 16);
    r.w = __uint_as_float(((u32)(unsigned short)s.w) << 16);
    return r;
}

// -------------------------------- copy inp -> out, zero o-cols, produce Abf -
__global__ __launch_bounds__(256) void mbd_copy_kernel(const float* __restrict__ in,
                                                       float* __restrict__ out,
                                                       short* __restrict__ Abf) {
    int row = blockIdx.y;
    int c4  = blockIdx.x * 256 + threadIdx.x;   // f32x4 index within out row
    if (c4 < 2048) {
        f32x4 v = *(const f32x4*)(in + (size_t)row * FEAT + c4 * 4);
        *(f32x4*)(out + (size_t)row * OUTW + c4 * 4) = v;
        *(bf16x4*)(Abf + (size_t)row * FEAT + c4 * 4) = cvt4(v.x, v.y, v.z, v.w);
    } else if (c4 < 2080) {
        *(f32x4*)(out + (size_t)row * OUTW + c4 * 4) = (f32x4){0.f, 0.f, 0.f, 0.f};
    }
}

// ---------------------------------------------------------------- GEMM ------
// Mt_part[kc][col][row] (bf16) = (Abf[:, kc-slice] @ T[kc-slice, :])^T.
// Depth-2 DMA ring (3 LDS slots), counted vmcnt(4), raw s_barrier - loads are
// NEVER drained to 0 in the loop (T3/T4). Per wave per tile = exactly 4
// gl_lds16 (2 A + 2 B); vmcnt unit = 4.
// A: bf16 [m][k] packed 64-B rows, XOR swizzle baked into per-lane GLOBAL src
//    (storage quad = logical quad ^ (row&3)) -> frag ds_read_b128 uniform banks.
// B: f32 [k][n] linear slot -> shared transpose-cvt -> Bbf bf16 [n][k] pitch-40.
__global__ __launch_bounds__(512, 2) void mbd_gemm_kernel(const short* __restrict__ Abf,
                                                          const float* __restrict__ T,
                                                          short* __restrict__ Mt) {
    __shared__ __align__(16) short Als[3][BM * BK];   // 3 x 16 KB
    __shared__ __align__(16) float Bfs[3][BK * BN];   // 3 x 16 KB
    __shared__ __align__(16) short Bbf[2][BN * BBP];  // 2 x 10 KB

    const int tid = threadIdx.x, lane = tid & 63, l15 = lane & 15, w = tid >> 6;
    const int wm = (w & 3) * 64, wn = (w >> 2) * 64;   // wave tile 64x64

    const int kc = blockIdx.x & 15;          // bx%8 == kc%8: A slab L2-resident/XCD
    const int n0 = (blockIdx.x >> 4) * BN;
    const int kbase = kc * KC;

    // ---- staging descriptors: per wave 2 A chunks + 2 B chunks of 1 KB
    const short* asrc[2]; const float* bsrc[2];
    int aofs[2], bofs[2];                    // LDS offsets within a slot
#pragma unroll
    for (int u = 0; u < 2; ++u) {
        const int g = w * 2 + u;                            // chunk 0..15
        // A: chunk g = rows g*16+(lane>>2); dest quad lane&3 holds logical
        // quad (lane&3)^(row&3) -> swizzle baked into source address.
        const int am = g * 16 + (lane >> 2);
        const int qs = (lane & 3) ^ ((lane >> 2) & 3);
        asrc[u] = Abf + (size_t)am * FEAT + kbase + qs * 8;
        aofs[u] = g * 512;                                  // shorts
        // B: chunk g = k-rows g*2+(lane>>5), 16-B piece (lane&31)*4 (linear)
        const int kr = g * 2 + (lane >> 5);
        bsrc[u] = T + (size_t)(kbase + kr) * NOUT + n0 + (lane & 31) * 4;
        bofs[u] = g * 256;                                  // floats
    }

    // ---- fragment LDS offsets (shorts within slot)
    int aro[4], bro[4];
#pragma unroll
    for (int m = 0; m < 4; ++m) {
        int row = wm + m * 16 + l15;
        aro[m] = row * BK + (((lane >> 4) ^ (row & 3)) * 8);
    }
#pragma unroll
    for (int n = 0; n < 4; ++n) bro[n] = (wn + n * 16 + l15) * BBP + (lane >> 4) * 8;

    // ---- transpose constants: thread owns col tn, k-quad th
    const int tn = tid & 127, th = tid >> 7;

    f32x4 acc[4][4];
#pragma unroll
    for (int m = 0; m < 4; ++m)
#pragma unroll
        for (int n = 0; n < 4; ++n) acc[m][n] = (f32x4){0.f, 0.f, 0.f, 0.f};

#define STAGE(tt, s)                                                          \
    {                                                                         \
        _Pragma("unroll")                                                     \
        for (int u = 0; u < 2; ++u)                                           \
            gl_lds16(asrc[u] + (tt) * BK, &Als[0][0] + (s) * (BM * BK) + aofs[u]); \
        _Pragma("unroll")                                                     \
        for (int u = 0; u < 2; ++u)                                           \
            gl_lds16(bsrc[u] + (size_t)(tt) * BK * NOUT,                      \
                     &Bfs[0][0] + (s) * (BK * BN) + bofs[u]);                 \
    }

#define TRANSPOSE(tt)                                                         \
    {                                                                         \
        const float* bp = &Bfs[0][0] + ((tt) % 3) * (BK * BN);                \
        float v[8];                                                           \
        _Pragma("unroll")                                                     \
        for (int j = 0; j < 8; ++j) v[j] = bp[(th * 8 + j) * BN + tn];        \
        bf16x4 lo = cvt4(v[0], v[1], v[2], v[3]);                             \
        bf16x4 hi = cvt4(v[4], v[5], v[6], v[7]);                             \
        bf16x8 q;                                                             \
        q[0] = lo.x; q[1] = lo.y; q[2] = lo.z; q[3] = lo.w;                   \
        q[4] = hi.x; q[5] = hi.y; q[6] = hi.z; q[7] = hi.w;                   \
        *(bf16x8*)(&Bbf[0][0] + ((tt) & 1) * (BN * BBP) + tn * BBP + th * 8) = q; \
    }

    // ---- prologue: stage tiles 0,1; wait tile 0 (tile 1 stays in flight)
    STAGE(0, 0);
    STAGE(1, 1);
    asm volatile("s_waitcnt vmcnt(4)" ::: "memory");
    __builtin_amdgcn_s_barrier();
    asm volatile("" ::: "memory");
    TRANSPOSE(0);

#pragma unroll
    for (int kt = 0; kt < NSTEP; ++kt) {
        // barrier0: my transpose/frag LDS ops done; slot (kt+2)%3 reusable
        asm volatile("s_waitcnt lgkmcnt(0)" ::: "memory");
        __builtin_amdgcn_s_barrier();
        asm volatile("" ::: "memory");
        __builtin_amdgcn_sched_barrier(0);
        if (kt + 2 < NSTEP) STAGE(kt + 2, (kt + 2) % 3);
        __builtin_amdgcn_sched_barrier(0);
        if (kt + 1 < NSTEP) {
            // prove tile kt+1 landed; keep tile kt+2 (4 newest) in flight
            if (kt + 2 < NSTEP) asm volatile("s_waitcnt vmcnt(4)" ::: "memory");
            else                asm volatile("s_waitcnt vmcnt(0)" ::: "memory");
            __builtin_amdgcn_s_barrier();                 // barrier1
            asm volatile("" ::: "memory");
            __builtin_amdgcn_sched_barrier(0);
            TRANSPOSE(kt + 1);                            // -> Bbf[(kt+1)&1]
        }
        // fragments + MFMA on tile kt (Als slot kt%3, Bbf[kt&1])
        const short* ap = &Als[0][0] + (kt % 3) * (BM * BK);
        const short* bq = &Bbf[0][0] + (kt & 1) * (BN * BBP);
        bf16x8 af[4], bf[4];
#pragma unroll
        for (int m = 0; m < 4; ++m) af[m] = *(const bf16x8*)(ap + aro[m]);
#pragma unroll
        for (int n = 0; n < 4; ++n) bf[n] = *(const bf16x8*)(bq + bro[n]);
        __builtin_amdgcn_s_setprio(1);
#pragma unroll
        for (int m = 0; m < 4; ++m)
#pragma unroll
            for (int n = 0; n < 4; ++n)
                acc[m][n] = __builtin_amdgcn_mfma_f32_16x16x32_bf16(
                    af[m], bf[n], acc[m][n], 0, 0, 0);
        __builtin_amdgcn_s_setprio(0);
    }
#undef STAGE
#undef TRANSPOSE

    // epilogue: C/D layout col = l&15, row = (l>>4)*4 + r  [m89-verified]
    short* Mp = Mt + (size_t)kc * NOUT * NS;
    const int r0 = (lane >> 4) * 4;
#pragma unroll
    for (int m = 0; m < 4; ++m)
#pragma unroll
        for (int n = 0; n < 4; ++n) {
            int col = n0 + wn + n * 16 + l15;
            int row = wm + m * 16 + r0;
            *(bf16x4*)&Mp[(size_t)col * NS + row] =
                cvt4(acc[m][n].x, acc[m][n].y, acc[m][n].z, acc[m][n].w);
        }
}

// ---------------------------------------------------------------- pairwise --
// block (b, jhalf): o_part[i,b] = sum_{j in half} exp(-sum_c |M[i,c]-M[j,c]|)
// Mt bf16 layout [p][col][row]; fold reads fully coalesced.
__global__ __launch_bounds__(256) void mbd_pair_kernel(const short* __restrict__ Mt,
                                                       float* __restrict__ out) {
    const int b = blockIdx.x >> 1, jh = blockIdx.x & 1;
    const int t = threadIdx.x;
    __shared__ float ldsT[CD][NS];       // [c][row] 16 KB
    __shared__ float rows[NS][20];       // [row][c] padded (80 B pitch) 20 KB

#pragma unroll
    for (int u4 = 0; u4 < 4; ++u4) {
        int u = t + u4 * 256;
        int c = u >> 6, r4 = (u & 63) * 4;
        f32x4 v = (f32x4){0.f, 0.f, 0.f, 0.f};
#pragma unroll
        for (int p = 0; p < KSPLIT; ++p)
            v += bf4_to_f32(*(const bf16x4*)(Mt +
                     ((size_t)p * NOUT + (size_t)b * CD + c) * NS + r4));
        *(f32x4*)&ldsT[c][r4] = v;
    }
    __syncthreads();

    float my[16];
#pragma unroll
    for (int c = 0; c < 16; ++c) my[c] = ldsT[c][t];   // contiguous -> conflict-free
#pragma unroll
    for (int c = 0; c < 16; ++c) rows[t][c] = my[c];
    __syncthreads();

    float o0 = 0.f, o1 = 0.f;
    const int jbase = jh * 128;
    for (int jj = 0; jj < 128; jj += 2) {
#pragma unroll
        for (int s = 0; s < 2; ++s) {
            const float* rp = &rows[jbase + jj + s][0];   // uniform -> broadcast
            float d0 = 0.f, d1 = 0.f, d2 = 0.f, d3 = 0.f;
#pragma unroll
            for (int q = 0; q < 4; ++q) {
                f32x4 r = *(const f32x4*)(rp + q * 4);
                d0 += fabsf(my[q * 4 + 0] - r.x);
                d1 += fabsf(my[q * 4 + 1] - r.y);
                d2 += fabsf(my[q * 4 + 2] - r.z);
                d3 += fabsf(my[q * 4 + 3] - r.w);
            }
            float d = (d0 + d1) + (d2 + d3);
            if (s == 0) o0 += __expf(-d); else o1 += __expf(-d);
        }
    }
    // exactly two addends per address -> f32 add commutative -> deterministic
    atomicAdd(&out[(size_t)t * OUTW + FEAT + b], o0 + o1);
}

// ---------------------------------------------------------------- launch ----
extern "C" void kernel_launch(void* const* d_in, const int* in_sizes, int n_in,
                              void* d_out, int out_size, void* d_ws, size_t ws_size,
                              hipStream_t stream) {
    const float* inp = (const float*)d_in[0];
    const float* T   = (const float*)d_in[1];
    float* out = (float*)d_out;

    // ws layout: Abf bf16 [256][8192] = 4 MiB, then Mt bf16 [16][2048][256] = 16 MiB.
    short* Abf = (short*)d_ws;
    short* Mt  = Abf + (size_t)NS * FEAT;

    mbd_copy_kernel<<<dim3(9, 256), 256, 0, stream>>>(inp, out, Abf);
    mbd_gemm_kernel<<<256, 512, 0, stream>>>(Abf, T, Mt);
    mbd_pair_kernel<<<BD * 2, 256, 0, stream>>>(Mt, out);
}